// Round 10
// baseline (1710.575 us; speedup 1.0000x reference)
//
#include <hip/hip_runtime.h>
#include <hip/hip_bf16.h>
#include <math.h>

#define D_   512
#define H_   8
#define HD_  64
#define L_   6
#define FF_  2048
#define IN_  32
#define OUT_ 3
#define S_   512
#define B_   32
#define M_   (B_ * S_)   // 16384 token rows

typedef __attribute__((ext_vector_type(8))) short short8;
typedef __attribute__((ext_vector_type(4))) float floatx4;

__device__ __forceinline__ float gelu_f(float x) {
    return 0.5f * x * (1.0f + erff(x * 0.7071067811865475f));
}
__device__ __forceinline__ float bf2f(unsigned short u) {
    union { unsigned int i; float f; } c; c.i = ((unsigned)u) << 16; return c.f;
}
__device__ __forceinline__ unsigned short f2bf(float v) {
    __hip_bfloat16 t = __float2bfloat16(v);
    return *(unsigned short*)&t;
}
__device__ __forceinline__ void async16(const void* g, void* l) {
    __builtin_amdgcn_global_load_lds(
        (const __attribute__((address_space(1))) unsigned int*)g,
        (__attribute__((address_space(3))) unsigned int*)l, 16, 0, 0);
}

// ---------------------------------------------------------------------------
// bf16 MFMA GEMM: C[M,N] = A[M,K]bf16 @ W^T[N,K]bf16 + bias (+ R fp32),
// optional GELU, fp32 or bf16 out. M=16384 fixed, N mult 128, K mult 32.
// Pipelined K-loop with BK=32 stages: 2-stage LDS double buffer is only
// 32 KB (epilogue overlay 33.8 KB dominates -> 4 blocks/CU, 16 waves) while
// keeping issue-ahead order (barrier -> prefetch i+1 -> compute i) so the
// vmcnt(0) drain before each barrier waits on loads issued a full compute
// phase earlier. R8 had occupancy w/o pipeline (65us), R9 pipeline w/o
// occupancy (67us) — this takes both. XCD swizzle (gridDim.y % 8 == 0).
// ---------------------------------------------------------------------------
template<int DO_GELU, int OUT_BF16, int ADD_RES>
__global__ __launch_bounds__(256)
void gemm_mfma_k(const __hip_bfloat16* __restrict__ A,
                 const __hip_bfloat16* __restrict__ WT,
                 const float* __restrict__ bias,
                 const float* __restrict__ R,
                 void* __restrict__ C,
                 int N, int K) {
    // smem overlay: [0,32K) = 2 stages x (A 8K | B 8K) for the K-loop;
    // epilogue Ep 64x132 fp32 (33.8K) overlays after the K-loop.
    __shared__ __align__(16) char smem[34816];
    float* Ep = (float*)smem;

    const int tid  = threadIdx.x;
    const int lane = tid & 63;
    const int wave = tid >> 6;

    // XCD-aware remap: all n-blocks of an m-slab on one XCD.
    const int Lid = blockIdx.y * gridDim.x + blockIdx.x;
    const int xcd = Lid & 7;
    const int idx = Lid >> 3;
    const int gx  = gridDim.x, gy8 = gridDim.y >> 3;
    const int m0 = (xcd * gy8 + idx / gx) * 128;
    const int n0 = (idx % gx) * 128;

    const int wm = (wave >> 1) * 64, wn = (wave & 1) * 64;

    // staging: row = tid/4, col-block = (tid&3) XOR (row&3)  (8 shorts each)
    const int srow = tid >> 2;
    const int scol = ((tid & 3) ^ (srow & 3)) * 8;
    const short* Ag = (const short*)A + (long)(m0 + srow) * K + scol;
    const short* Bg = (const short*)WT + (long)(n0 + srow) * K + scol;

    floatx4 acc[4][4];
    #pragma unroll
    for (int i = 0; i < 4; i++)
        #pragma unroll
        for (int j = 0; j < 4; j++) acc[i][j] = (floatx4)0.f;

    const int r = lane & 15, q = lane >> 4;
    const int qa = (q ^ (r & 3)) * 8;   // de-swizzled col-block offset

    const int nIter = K >> 5;           // K/32 stages

    // prologue: stage 0 loads (A 8KB: 2 issues; B 8KB: 2 issues)
    {
        short* As_ = (short*)smem;
        short* Bs_ = (short*)smem + 4096;
        async16(Ag,                As_ + tid * 8);
        async16(Ag + (long)64 * K, As_ + 2048 + tid * 8);
        async16(Bg,                Bs_ + tid * 8);
        async16(Bg + (long)64 * K, Bs_ + 2048 + tid * 8);
    }

    for (int i = 0; i < nIter; i++) {
        __syncthreads();   // drains stage-i loads (issued one compute ago)

        if (i + 1 < nIter) {            // prefetch stage i+1 (other buffer)
            const int k0 = (i + 1) << 5;
            short* As_ = (short*)smem + ((i + 1) & 1) * 8192;
            short* Bs_ = As_ + 4096;
            async16(Ag + k0,                As_ + tid * 8);
            async16(Ag + (long)64 * K + k0, As_ + 2048 + tid * 8);
            async16(Bg + k0,                Bs_ + tid * 8);
            async16(Bg + (long)64 * K + k0, Bs_ + 2048 + tid * 8);
        }

        const short* As_ = (const short*)smem + (i & 1) * 8192;
        const short* Bs_ = As_ + 4096;
        short8 af[4], bf[4];
        #pragma unroll
        for (int t = 0; t < 4; t++)
            af[t] = *(const short8*)&As_[(wm + t * 16 + r) * 32 + qa];
        #pragma unroll
        for (int t = 0; t < 4; t++)
            bf[t] = *(const short8*)&Bs_[(wn + t * 16 + r) * 32 + qa];
        #pragma unroll
        for (int i2 = 0; i2 < 4; i2++)
            #pragma unroll
            for (int j = 0; j < 4; j++)
                acc[i2][j] = __builtin_amdgcn_mfma_f32_16x16x32_bf16(
                    af[i2], bf[j], acc[i2][j], 0, 0, 0);
    }
    __syncthreads();   // all LDS reads done before Ep overlay

    // ---- epilogue: restage through LDS, coalesced postprocess + store ----
    const int erow = tid >> 5;          // 0..7
    const int ecol = (tid & 31) * 4;    // 0..124, float4 granularity
    const float4 bvec = *(const float4*)&bias[n0 + ecol];

    #pragma unroll
    for (int pass = 0; pass < 2; pass++) {
        if (pass) __syncthreads();      // pass0 Ep reads done before overwrite
        if ((wave >> 1) == pass) {
            #pragma unroll
            for (int i = 0; i < 4; i++)
                #pragma unroll
                for (int j = 0; j < 4; j++)
                    #pragma unroll
                    for (int rg = 0; rg < 4; rg++)
                        Ep[(i * 16 + q * 4 + rg) * 132 + wn + j * 16 + r] =
                            acc[i][j][rg];
        }
        __syncthreads();
        #pragma unroll
        for (int it = 0; it < 8; it++) {
            const int row = it * 8 + erow;   // 0..63 within half-tile
            const long grow = (long)(m0 + pass * 64 + row) * N + n0 + ecol;
            const float4 v = *(const float4*)&Ep[row * 132 + ecol];
            float o0 = v.x + bvec.x, o1 = v.y + bvec.y;
            float o2 = v.z + bvec.z, o3 = v.w + bvec.w;
            if (DO_GELU) {
                o0 = gelu_f(o0); o1 = gelu_f(o1);
                o2 = gelu_f(o2); o3 = gelu_f(o3);
            }
            if (ADD_RES) {
                const float4 rv = *(const float4*)&R[grow];
                o0 += rv.x; o1 += rv.y; o2 += rv.z; o3 += rv.w;
            }
            if (OUT_BF16) {
                ushort4 pk;
                pk.x = f2bf(o0); pk.y = f2bf(o1);
                pk.z = f2bf(o2); pk.w = f2bf(o3);
                *(ushort4*)((unsigned short*)C + grow) = pk;
            } else {
                *(float4*)((float*)C + grow) = make_float4(o0, o1, o2, o3);
            }
        }
    }
}

// ---------------------------------------------------------------------------
// WT[l][n][k] = (bf16) W[l][k][n]
// ---------------------------------------------------------------------------
__global__ __launch_bounds__(256)
void transpose_cast_k(const float* __restrict__ W, __hip_bfloat16* __restrict__ WT,
                      int K, int N) {
    __shared__ float tile[32][33];
    const float* Wl = W + (long)blockIdx.z * K * N;
    __hip_bfloat16* WTl = WT + (long)blockIdx.z * K * N;
    const int n0 = blockIdx.x * 32, k0 = blockIdx.y * 32;
    const int tx = threadIdx.x & 31, ty = threadIdx.x >> 5;
    for (int rr = ty; rr < 32; rr += 8)
        tile[rr][tx] = Wl[(long)(k0 + rr) * N + n0 + tx];
    __syncthreads();
    for (int rr = ty; rr < 32; rr += 8)
        WTl[(long)(n0 + rr) * K + k0 + tx] = __float2bfloat16(tile[tx][rr]);
}

// ---------------------------------------------------------------------------
// fp32 tiled GEMM (in-proj only: M=16384, N=512, K=32)
// ---------------------------------------------------------------------------
template<int DO_GELU>
__global__ __launch_bounds__(256)
void gemm_bias_k(const float* __restrict__ A, long lda,
                 const float* __restrict__ W,
                 const float* __restrict__ bias,
                 float* __restrict__ C,
                 int M, int N, int K) {
    __shared__ float As[16][64];
    __shared__ float Ws[16][64];
    const int tx = threadIdx.x;
    const int ty = threadIdx.y;
    const int tid = ty * 16 + tx;
    const int m0 = blockIdx.y * 64;
    const int n0 = blockIdx.x * 64;
    float acc[4][4] = {};
    for (int k0 = 0; k0 < K; k0 += 16) {
        #pragma unroll
        for (int e = tid; e < 64 * 16; e += 256) {
            int m = e >> 4, k = e & 15;
            float v = 0.f;
            if (m0 + m < M) v = A[(long)(m0 + m) * lda + k0 + k];
            As[k][m] = v;
        }
        #pragma unroll
        for (int e = tid; e < 16 * 64; e += 256) {
            int k = e >> 6, n = e & 63;
            float v = 0.f;
            if (n0 + n < N) v = W[(long)(k0 + k) * N + n0 + n];
            Ws[k][n] = v;
        }
        __syncthreads();
        #pragma unroll
        for (int kk = 0; kk < 16; kk++) {
            float a[4], w[4];
            #pragma unroll
            for (int i = 0; i < 4; i++) a[i] = As[kk][ty * 4 + i];
            #pragma unroll
            for (int j = 0; j < 4; j++) w[j] = Ws[kk][tx * 4 + j];
            #pragma unroll
            for (int i = 0; i < 4; i++)
                #pragma unroll
                for (int j = 0; j < 4; j++)
                    acc[i][j] += a[i] * w[j];
        }
        __syncthreads();
    }
    #pragma unroll
    for (int i = 0; i < 4; i++) {
        int m = m0 + ty * 4 + i;
        if (m >= M) continue;
        #pragma unroll
        for (int j = 0; j < 4; j++) {
            int n = n0 + tx * 4 + j;
            if (n >= N) continue;
            float v = acc[i][j] + bias[n];
            if (DO_GELU) v = gelu_f(v);
            C[(long)m * N + n] = v;
        }
    }
}

// ---------------------------------------------------------------------------
// Wave-per-row LN: H/Hb = layernorm(X)*g+be. 4 rows per 256-thr block.
// ---------------------------------------------------------------------------
__global__ __launch_bounds__(256)
void ln_k(const float* __restrict__ X,
          const float* __restrict__ g,
          const float* __restrict__ be,
          float* __restrict__ H,
          __hip_bfloat16* __restrict__ Hb) {
    const int row = blockIdx.x * 4 + (threadIdx.x >> 6);
    const int lane = threadIdx.x & 63;
    const float* xp = X + (long)row * D_ + lane * 8;
    const float4 a = *(const float4*)xp;
    const float4 c = *(const float4*)(xp + 4);
    float s = a.x + a.y + a.z + a.w + c.x + c.y + c.z + c.w;
    #pragma unroll
    for (int off = 1; off < 64; off <<= 1) s += __shfl_xor(s, off);
    const float mu = s * (1.0f / D_);
    float d[8] = { a.x - mu, a.y - mu, a.z - mu, a.w - mu,
                   c.x - mu, c.y - mu, c.z - mu, c.w - mu };
    float ss = 0.f;
    #pragma unroll
    for (int e = 0; e < 8; e++) ss += d[e] * d[e];
    #pragma unroll
    for (int off = 1; off < 64; off <<= 1) ss += __shfl_xor(ss, off);
    const float inv = 1.0f / sqrtf(ss * (1.0f / D_) + 1e-5f);
    const float4 g0 = *(const float4*)(g + lane * 8);
    const float4 g1 = *(const float4*)(g + lane * 8 + 4);
    const float4 e0 = *(const float4*)(be + lane * 8);
    const float4 e1 = *(const float4*)(be + lane * 8 + 4);
    const float gv[8] = { g0.x, g0.y, g0.z, g0.w, g1.x, g1.y, g1.z, g1.w };
    const float ev[8] = { e0.x, e0.y, e0.z, e0.w, e1.x, e1.y, e1.z, e1.w };
    float o[8];
    short8 pk;
    #pragma unroll
    for (int e = 0; e < 8; e++) {
        o[e] = d[e] * inv * gv[e] + ev[e];
        pk[e] = (short)f2bf(o[e]);
    }
    float* hp = H + (long)row * D_ + lane * 8;
    *(float4*)hp = make_float4(o[0], o[1], o[2], o[3]);
    *(float4*)(hp + 4) = make_float4(o[4], o[5], o[6], o[7]);
    *(short8*)((unsigned short*)Hb + (long)row * D_ + lane * 8) = pk;
}

// ---------------------------------------------------------------------------
// h = gelu(layernorm(X)) + pe ; also bf16 copy hb  (runs once)
// ---------------------------------------------------------------------------
__global__ __launch_bounds__(256)
void ln_gelu_pos_k(const float* __restrict__ X,
                   const float* __restrict__ g,
                   const float* __restrict__ be,
                   float* __restrict__ Hout,
                   __hip_bfloat16* __restrict__ Hb) {
    const int row = blockIdx.x;
    const int s = row & (S_ - 1);
    const int t = threadIdx.x;
    const float* x = X + (long)row * D_;
    float v0 = x[t], v1 = x[t + 256];
    __shared__ float red[256];
    red[t] = v0 + v1;
    __syncthreads();
    for (int off = 128; off; off >>= 1) {
        if (t < off) red[t] += red[t + off];
        __syncthreads();
    }
    float mu = red[0] * (1.0f / D_);
    __syncthreads();
    float d0 = v0 - mu, d1 = v1 - mu;
    red[t] = d0 * d0 + d1 * d1;
    __syncthreads();
    for (int off = 128; off; off >>= 1) {
        if (t < off) red[t] += red[t + off];
        __syncthreads();
    }
    float var = red[0] * (1.0f / D_);
    float inv = 1.0f / sqrtf(var + 1e-5f);
    float o0 = gelu_f(d0 * inv * g[t] + be[t]);
    float o1 = gelu_f(d1 * inv * g[t + 256] + be[t + 256]);
    {
        int d = t, i = d >> 1;
        float dv = expf((float)(2 * i) * (-9.210340371976184f / 512.0f));
        float ang = (float)s * dv;
        o0 += (d & 1) ? cosf(ang) : sinf(ang);
    }
    {
        int d = t + 256, i = d >> 1;
        float dv = expf((float)(2 * i) * (-9.210340371976184f / 512.0f));
        float ang = (float)s * dv;
        o1 += (d & 1) ? cosf(ang) : sinf(ang);
    }
    Hout[(long)row * D_ + t] = o0;
    Hout[(long)row * D_ + t + 256] = o1;
    Hb[(long)row * D_ + t] = __float2bfloat16(o0);
    Hb[(long)row * D_ + t + 256] = __float2bfloat16(o1);
}

// ---------------------------------------------------------------------------
// MFMA flash attention (verified Round-4 structure, unchanged)
// ---------------------------------------------------------------------------
#define LDT 72
__global__ __launch_bounds__(256)
void attn_mfma_k(const __hip_bfloat16* __restrict__ qkv,
                 __hip_bfloat16* __restrict__ O) {
    const int qt = blockIdx.x;
    const int bh = blockIdx.y;
    const int b = bh >> 3, h = bh & (H_ - 1);
    const int tid = threadIdx.x;
    const int wave = tid >> 6, lane = tid & 63;
    const int ln = lane & 15, quad = lane >> 4;
    const int wm = wave * 32;
    const int i0 = qt * 128;

    __shared__ unsigned short Qs[128 * LDT];
    __shared__ unsigned short Ks[64 * LDT];
    __shared__ unsigned short Vt[64 * LDT];
    __shared__ unsigned short Ps[128 * LDT];
    __shared__ float stat[128];

    const unsigned short* base = (const unsigned short*)qkv + (long)b * S_ * (3 * D_);

    {
        const int r0 = tid >> 3, c0 = (tid & 7) * 8;
        #pragma unroll
        for (int i = 0; i < 4; i++) {
            const int rw = i * 32 + r0;
            *(short8*)&Qs[rw * LDT + c0] =
                *(const short8*)(base + (long)(i0 + rw) * (3 * D_) + h * HD_ + c0);
        }
    }

    float m_i[2] = { -INFINITY, -INFINITY };
    float l_i[2] = { 0.f, 0.f };
    floatx4 o_acc[2][4];
    #pragma unroll
    for (int i = 0; i < 2; i++)
        #pragma unroll
        for (int j = 0; j < 4; j++) o_acc[i][j] = (floatx4)0.f;

    const int kr = tid >> 2, kc = (tid & 3) * 16;
    const int vj = tid & 63, vc = (tid >> 6) * 16;

    const int ktmax = 2 * qt + 1;
    for (int kt = 0; kt <= ktmax; kt++) {
        const int j0 = kt * 64;
        {
            const unsigned short* kp = base + (long)(j0 + kr) * (3 * D_) + D_ + h * HD_ + kc;
            *(short8*)&Ks[kr * LDT + kc]     = *(const short8*)(kp);
            *(short8*)&Ks[kr * LDT + kc + 8] = *(const short8*)(kp + 8);
            const unsigned short* vp = base + (long)(j0 + vj) * (3 * D_) + 2 * D_ + h * HD_ + vc;
            short8 v0 = *(const short8*)(vp);
            short8 v1 = *(const short8*)(vp + 8);
            #pragma unroll
            for (int e = 0; e < 8; e++) {
                Vt[(vc + e) * LDT + vj]     = (unsigned short)v0[e];
                Vt[(vc + 8 + e) * LDT + vj] = (unsigned short)v1[e];
            }
        }
        __syncthreads();

        floatx4 sa[4][2];
        #pragma unroll
        for (int mt = 0; mt < 4; mt++)
            #pragma unroll
            for (int nt = 0; nt < 2; nt++) sa[mt][nt] = (floatx4)0.f;
        #pragma unroll
        for (int c = 0; c < 2; c++) {
            short8 kf[4], qf[2];
            #pragma unroll
            for (int mt = 0; mt < 4; mt++)
                kf[mt] = *(const short8*)&Ks[(mt * 16 + ln) * LDT + c * 32 + quad * 8];
            #pragma unroll
            for (int nt = 0; nt < 2; nt++)
                qf[nt] = *(const short8*)&Qs[(wm + nt * 16 + ln) * LDT + c * 32 + quad * 8];
            #pragma unroll
            for (int mt = 0; mt < 4; mt++)
                #pragma unroll
                for (int nt = 0; nt < 2; nt++)
                    sa[mt][nt] = __builtin_amdgcn_mfma_f32_16x16x32_bf16(
                        kf[mt], qf[nt], sa[mt][nt], 0, 0, 0);
        }

        const bool domask = (kt >= 2 * qt);
        #pragma unroll
        for (int nt = 0; nt < 2; nt++) {
            const int qg = i0 + wm + nt * 16 + ln;
            float mx = -INFINITY;
            #pragma unroll
            for (int mt = 0; mt < 4; mt++)
                #pragma unroll
                for (int rg = 0; rg < 4; rg++) {
                    float v = sa[mt][nt][rg] * 0.125f;
                    if (domask && (j0 + mt * 16 + quad * 4 + rg > qg)) v = -INFINITY;
                    sa[mt][nt][rg] = v;
                    mx = fmaxf(mx, v);
                }
            mx = fmaxf(mx, __shfl_xor(mx, 16));
            mx = fmaxf(mx, __shfl_xor(mx, 32));
            const float mn = fmaxf(m_i[nt], mx);
            const float alpha = __expf(m_i[nt] - mn);
            m_i[nt] = mn;
            float ls = 0.f;
            #pragma unroll
            for (int mt = 0; mt < 4; mt++) {
                ushort4 pk;
                float p0 = __expf(sa[mt][nt][0] - mn);
                float p1 = __expf(sa[mt][nt][1] - mn);
                float p2 = __expf(sa[mt][nt][2] - mn);
                float p3 = __expf(sa[mt][nt][3] - mn);
                ls += p0 + p1 + p2 + p3;
                pk.x = f2bf(p0); pk.y = f2bf(p1); pk.z = f2bf(p2); pk.w = f2bf(p3);
                *(ushort4*)&Ps[(wm + nt * 16 + ln) * LDT + mt * 16 + quad * 4] = pk;
            }
            ls += __shfl_xor(ls, 16);
            ls += __shfl_xor(ls, 32);
            l_i[nt] = l_i[nt] * alpha + ls;
            if (quad == 0) stat[wm + nt * 16 + ln] = alpha;
        }

        #pragma unroll
        for (int mt2 = 0; mt2 < 2; mt2++) {
            #pragma unroll
            for (int rg = 0; rg < 4; rg++) {
                const float a = stat[wm + mt2 * 16 + quad * 4 + rg];
                #pragma unroll
                for (int nt = 0; nt < 4; nt++) o_acc[mt2][nt][rg] *= a;
            }
        }

        #pragma unroll
        for (int c = 0; c < 2; c++) {
            short8 pf[2], vf[4];
            #pragma unroll
            for (int mt2 = 0; mt2 < 2; mt2++)
                pf[mt2] = *(const short8*)&Ps[(wm + mt2 * 16 + ln) * LDT + c * 32 + quad * 8];
            #pragma unroll
            for (int nt = 0; nt < 4; nt++)
                vf[nt] = *(const short8*)&Vt[(nt * 16 + ln) * LDT + c * 32 + quad * 8];
            #pragma unroll
            for (int mt2 = 0; mt2 < 2; mt2++)
                #pragma unroll
                for (int nt = 0; nt < 4; nt++)
                    o_acc[mt2][nt] = __builtin_amdgcn_mfma_f32_16x16x32_bf16(
                        pf[mt2], vf[nt], o_acc[mt2][nt], 0, 0, 0);
        }
        __syncthreads();
    }

    if (quad == 0) {
        stat[wm + ln]      = l_i[0];
        stat[wm + 16 + ln] = l_i[1];
    }
    unsigned short* Og = (unsigned short*)O;
    #pragma unroll
    for (int mt2 = 0; mt2 < 2; mt2++) {
        #pragma unroll
        for (int rg = 0; rg < 4; rg++) {
            const float linv = 1.0f / stat[wm + mt2 * 16 + quad * 4 + rg];
            const long row = (long)(b * S_ + i0 + wm + mt2 * 16 + quad * 4 + rg);
            #pragma unroll
            for (int nt = 0; nt < 4; nt++)
                Og[row * D_ + h * HD_ + nt * 16 + ln] =
                    f2bf(o_acc[mt2][nt][rg] * linv);
        }
    }
}

// ---------------------------------------------------------------------------
// Head kernels
// ---------------------------------------------------------------------------
__global__ __launch_bounds__(256)
void head1_k(const float* __restrict__ h, const float* __restrict__ w1,
             const float* __restrict__ b1, float* __restrict__ th) {
    __shared__ float hs[D_];
    const int b = blockIdx.x, n = threadIdx.x;
    const float* hr = h + (long)(b * S_ + S_ - 1) * D_;
    hs[n] = hr[n];
    hs[n + 256] = hr[n + 256];
    __syncthreads();
    float s = 0.f;
    #pragma unroll 8
    for (int k = 0; k < D_; k++) s += hs[k] * w1[(long)k * 256 + n];
    th[b * 256 + n] = gelu_f(s + b1[n]);
}

__global__ __launch_bounds__(64)
void head2_k(const float* __restrict__ th, const float* __restrict__ w2,
             const float* __restrict__ b2, float* __restrict__ out) {
    const int b = blockIdx.x, lane = threadIdx.x;
    const float* t = th + b * 256;
    float s0 = 0.f, s1 = 0.f, s2 = 0.f;
    #pragma unroll
    for (int e = 0; e < 4; e++) {
        const int k = lane * 4 + e;
        const float tv = t[k];
        s0 += tv * w2[k * 3 + 0];
        s1 += tv * w2[k * 3 + 1];
        s2 += tv * w2[k * 3 + 2];
    }
    #pragma unroll
    for (int off = 1; off < 64; off <<= 1) {
        s0 += __shfl_xor(s0, off);
        s1 += __shfl_xor(s1, off);
        s2 += __shfl_xor(s2, off);
    }
    if (lane == 0) {
        out[b * 3 + 0] = s0 + b2[0];
        out[b * 3 + 1] = s1 + b2[1];
        out[b * 3 + 2] = s2 + b2[2];
    }
}

// ---------------------------------------------------------------------------
extern "C" void kernel_launch(void* const* d_in, const int* in_sizes, int n_in,
                              void* d_out, int out_size, void* d_ws, size_t ws_size,
                              hipStream_t stream) {
    const float* x     = (const float*)d_in[0];
    const float* w_in  = (const float*)d_in[1];
    const float* b_in  = (const float*)d_in[2];
    const float* g_in  = (const float*)d_in[3];
    const float* be_in = (const float*)d_in[4];
    const float* w_qkv = (const float*)d_in[5];
    const float* b_qkv = (const float*)d_in[6];
    const float* w_out = (const float*)d_in[7];
    const float* b_out = (const float*)d_in[8];
    const float* g1    = (const float*)d_in[9];
    const float* be1   = (const float*)d_in[10];
    const float* w_ff1 = (const float*)d_in[11];
    const float* b_ff1 = (const float*)d_in[12];
    const float* w_ff2 = (const float*)d_in[13];
    const float* b_ff2 = (const float*)d_in[14];
    const float* g2    = (const float*)d_in[15];
    const float* be2   = (const float*)d_in[16];
    const float* w_h1  = (const float*)d_in[17];
    const float* b_h1  = (const float*)d_in[18];
    const float* w_h2  = (const float*)d_in[19];
    const float* b_h2  = (const float*)d_in[20];
    float* out = (float*)d_out;

    float* h    = (float*)d_ws;
    float* bufB = h + (long)M_ * D_;
    float* th   = bufB + (long)M_ * D_;
    __hip_bfloat16* hb    = (__hip_bfloat16*)(th + 32 * 256);
    __hip_bfloat16* attb  = hb + (long)M_ * D_;
    __hip_bfloat16* bufAb = attb + (long)M_ * D_;
    __hip_bfloat16* qkvT  = bufAb + (long)M_ * FF_;
    __hip_bfloat16* outT  = qkvT + (long)L_ * (3 * D_) * D_;
    __hip_bfloat16* ff1T  = outT + (long)L_ * D_ * D_;
    __hip_bfloat16* ff2T  = ff1T + (long)L_ * FF_ * D_;

    dim3 blk(16, 16);

    transpose_cast_k<<<dim3((3 * D_) / 32, D_ / 32, L_), 256, 0, stream>>>(w_qkv, qkvT, D_, 3 * D_);
    transpose_cast_k<<<dim3(D_ / 32, D_ / 32, L_), 256, 0, stream>>>(w_out, outT, D_, D_);
    transpose_cast_k<<<dim3(FF_ / 32, D_ / 32, L_), 256, 0, stream>>>(w_ff1, ff1T, D_, FF_);
    transpose_cast_k<<<dim3(D_ / 32, FF_ / 32, L_), 256, 0, stream>>>(w_ff2, ff2T, FF_, D_);

    gemm_bias_k<0><<<dim3(D_ / 64, M_ / 64), blk, 0, stream>>>(
        x, IN_, w_in, b_in, bufB, M_, D_, IN_);
    ln_gelu_pos_k<<<M_, 256, 0, stream>>>(bufB, g_in, be_in, h, hb);

    for (int l = 0; l < L_; l++) {
        // qkv -> bf16 bufAb
        gemm_mfma_k<0, 1, 0><<<dim3((3 * D_) / 128, M_ / 128), 256, 0, stream>>>(
            hb, qkvT + (long)l * (3 * D_) * D_, b_qkv + l * 3 * D_, nullptr,
            bufAb, 3 * D_, D_);
        attn_mfma_k<<<dim3(S_ / 128, B_ * H_), 256, 0, stream>>>(bufAb, attb);
        // out-proj + residual(h) -> fp32 bufB ; h = LN(bufB)
        gemm_mfma_k<0, 0, 1><<<dim3(D_ / 128, M_ / 128), 256, 0, stream>>>(
            attb, outT + (long)l * D_ * D_, b_out + l * D_, h,
            bufB, D_, D_);
        ln_k<<<M_ / 4, 256, 0, stream>>>(bufB, g1 + l * D_, be1 + l * D_, h, hb);
        // ff1 -> bf16 bufAb (gelu)
        gemm_mfma_k<1, 1, 0><<<dim3(FF_ / 128, M_ / 128), 256, 0, stream>>>(
            hb, ff1T + (long)l * FF_ * D_, b_ff1 + l * FF_, nullptr,
            bufAb, FF_, D_);
        // ff2 + residual(h) -> fp32 bufB ; h = LN(bufB)
        gemm_mfma_k<0, 0, 1><<<dim3(D_ / 128, M_ / 128), 256, 0, stream>>>(
            bufAb, ff2T + (long)l * D_ * FF_, b_ff2 + l * D_, h,
            bufB, D_, FF_);
        ln_k<<<M_ / 4, 256, 0, stream>>>(bufB, g2 + l * D_, be2 + l * D_, h, hb);
    }

    head1_k<<<B_, 256, 0, stream>>>(h, w_h1, b_h1, th);
    head2_k<<<B_, 64, 0, stream>>>(th, w_h2, b_h2, out);
}

// Round 11
// 1660.893 us; speedup vs baseline: 1.0299x; 1.0299x over previous
//
#include <hip/hip_runtime.h>
#include <hip/hip_bf16.h>
#include <math.h>

#define D_   512
#define H_   8
#define HD_  64
#define L_   6
#define FF_  2048
#define IN_  32
#define OUT_ 3
#define S_   512
#define B_   32
#define M_   (B_ * S_)   // 16384 token rows

typedef __attribute__((ext_vector_type(8))) short short8;
typedef __attribute__((ext_vector_type(4))) float floatx4;

__device__ __forceinline__ float gelu_f(float x) {
    return 0.5f * x * (1.0f + erff(x * 0.7071067811865475f));
}
__device__ __forceinline__ float bf2f(unsigned short u) {
    union { unsigned int i; float f; } c; c.i = ((unsigned)u) << 16; return c.f;
}
__device__ __forceinline__ unsigned short f2bf(float v) {
    __hip_bfloat16 t = __float2bfloat16(v);
    return *(unsigned short*)&t;
}
__device__ __forceinline__ void async16(const void* g, void* l) {
    __builtin_amdgcn_global_load_lds(
        (const __attribute__((address_space(1))) unsigned int*)g,
        (__attribute__((address_space(3))) unsigned int*)l, 16, 0, 0);
}

// ---------------------------------------------------------------------------
// bf16 MFMA GEMM: C[M,N] = A[M,K]bf16 @ W^T[N,K]bf16 + bias (+ R fp32),
// optional GELU, fp32 or bf16 out. M=16384 fixed, N mult 128, K mult 64.
// Two measured K-loop variants (R8 vs R9 A/B over 3 rounds):
//  PIPE=0: BK=64 per barrier, no cross-iter pipeline, 34.8 KB LDS ->
//          4 blocks/CU. Best for the GELU-heavy ff1 (65 us measured).
//  PIPE=1: BK=64 pipelined (barrier -> prefetch i+1 -> compute i), 64 KB
//          LDS -> 2 blocks/CU. Best for qkv/outproj/ff2 (R9 total best).
// Deeper pipelining is blocked: __syncthreads drains ALL outstanding DMA
// (m97 wall), so prefetch distance is capped at 1 compute phase.
// XCD swizzle (gridDim.y % 8 == 0). Coalesced LDS-restaged epilogue.
// ---------------------------------------------------------------------------
template<int DO_GELU, int OUT_BF16, int ADD_RES, int PIPE>
__global__ __launch_bounds__(256)
void gemm_mfma_k(const __hip_bfloat16* __restrict__ A,
                 const __hip_bfloat16* __restrict__ WT,
                 const float* __restrict__ bias,
                 const float* __restrict__ R,
                 void* __restrict__ C,
                 int N, int K) {
    __shared__ __align__(16) char smem[PIPE ? 65536 : 34816];
    float* Ep = (float*)smem;

    const int tid  = threadIdx.x;
    const int lane = tid & 63;
    const int wave = tid >> 6;

    // XCD-aware remap: all n-blocks of an m-slab on one XCD.
    const int Lid = blockIdx.y * gridDim.x + blockIdx.x;
    const int xcd = Lid & 7;
    const int idx = Lid >> 3;
    const int gx  = gridDim.x, gy8 = gridDim.y >> 3;
    const int m0 = (xcd * gy8 + idx / gx) * 128;
    const int n0 = (idx % gx) * 128;

    const int wm = (wave >> 1) * 64, wn = (wave & 1) * 64;

    // staging: row = tid/4, col-block = (tid&3) XOR (row&3)  (8 shorts each)
    const int srow = tid >> 2;
    const int scol = ((tid & 3) ^ (srow & 3)) * 8;
    const short* Ag = (const short*)A + (long)(m0 + srow) * K + scol;
    const short* Bg = (const short*)WT + (long)(n0 + srow) * K + scol;

    floatx4 acc[4][4];
    #pragma unroll
    for (int i = 0; i < 4; i++)
        #pragma unroll
        for (int j = 0; j < 4; j++) acc[i][j] = (floatx4)0.f;

    const int r = lane & 15, q = lane >> 4;
    const int qa = (q ^ (r & 3)) * 8;   // de-swizzled col-block offset

    if (PIPE) {
        // ---- R9 loop: 2-stage 64KB double buffer, issue-ahead ----
        const int nIter = K >> 6;
        {
            short* As_ = (short*)smem;
            short* Bs_ = (short*)(smem + 16384);
            async16(Ag,                     As_ + tid * 8);
            async16(Ag + (long)64 * K,      As_ + 2048 + tid * 8);
            async16(Ag + 32,                As_ + 4096 + tid * 8);
            async16(Ag + (long)64 * K + 32, As_ + 6144 + tid * 8);
            async16(Bg,                     Bs_ + tid * 8);
            async16(Bg + (long)64 * K,      Bs_ + 2048 + tid * 8);
            async16(Bg + 32,                Bs_ + 4096 + tid * 8);
            async16(Bg + (long)64 * K + 32, Bs_ + 6144 + tid * 8);
        }
        for (int i = 0; i < nIter; i++) {
            __syncthreads();   // drains stage-i loads (issued one iter ago)
            if (i + 1 < nIter) {
                const int k0 = (i + 1) << 6;
                short* As_ = (short*)(smem + ((i + 1) & 1) * 32768);
                short* Bs_ = (short*)(smem + ((i + 1) & 1) * 32768 + 16384);
                async16(Ag + k0,                     As_ + tid * 8);
                async16(Ag + (long)64 * K + k0,      As_ + 2048 + tid * 8);
                async16(Ag + k0 + 32,                As_ + 4096 + tid * 8);
                async16(Ag + (long)64 * K + k0 + 32, As_ + 6144 + tid * 8);
                async16(Bg + k0,                     Bs_ + tid * 8);
                async16(Bg + (long)64 * K + k0,      Bs_ + 2048 + tid * 8);
                async16(Bg + k0 + 32,                Bs_ + 4096 + tid * 8);
                async16(Bg + (long)64 * K + k0 + 32, Bs_ + 6144 + tid * 8);
            }
            const short* As_ = (const short*)(smem + (i & 1) * 32768);
            const short* Bs_ = (const short*)(smem + (i & 1) * 32768 + 16384);
            #pragma unroll
            for (int c = 0; c < 2; c++) {
                const short* Asc = As_ + c * 4096;
                const short* Bsc = Bs_ + c * 4096;
                short8 af[4], bf[4];
                #pragma unroll
                for (int t = 0; t < 4; t++)
                    af[t] = *(const short8*)&Asc[(wm + t * 16 + r) * 32 + qa];
                #pragma unroll
                for (int t = 0; t < 4; t++)
                    bf[t] = *(const short8*)&Bsc[(wn + t * 16 + r) * 32 + qa];
                #pragma unroll
                for (int i2 = 0; i2 < 4; i2++)
                    #pragma unroll
                    for (int j = 0; j < 4; j++)
                        acc[i2][j] = __builtin_amdgcn_mfma_f32_16x16x32_bf16(
                            af[i2], bf[j], acc[i2][j], 0, 0, 0);
            }
        }
        __syncthreads();
    } else {
        // ---- R8 loop: BK=64 per barrier pair, 34.8KB, no pipeline ----
        short* As0 = (short*)(smem);
        short* As1 = (short*)(smem + 8192);
        short* Bs0 = (short*)(smem + 16384);
        short* Bs1 = (short*)(smem + 24576);
        for (int k0 = 0; k0 < K; k0 += 64) {
            async16(Ag + k0,                     As0 + tid * 8);
            async16(Ag + (long)64 * K + k0,      As0 + 2048 + tid * 8);
            async16(Ag + k0 + 32,                As1 + tid * 8);
            async16(Ag + (long)64 * K + k0 + 32, As1 + 2048 + tid * 8);
            async16(Bg + k0,                     Bs0 + tid * 8);
            async16(Bg + (long)64 * K + k0,      Bs0 + 2048 + tid * 8);
            async16(Bg + k0 + 32,                Bs1 + tid * 8);
            async16(Bg + (long)64 * K + k0 + 32, Bs1 + 2048 + tid * 8);
            __syncthreads();
            #pragma unroll
            for (int c = 0; c < 2; c++) {
                const short* Asc = c ? As1 : As0;
                const short* Bsc = c ? Bs1 : Bs0;
                short8 af[4], bf[4];
                #pragma unroll
                for (int t = 0; t < 4; t++)
                    af[t] = *(const short8*)&Asc[(wm + t * 16 + r) * 32 + qa];
                #pragma unroll
                for (int t = 0; t < 4; t++)
                    bf[t] = *(const short8*)&Bsc[(wn + t * 16 + r) * 32 + qa];
                #pragma unroll
                for (int i = 0; i < 4; i++)
                    #pragma unroll
                    for (int j = 0; j < 4; j++)
                        acc[i][j] = __builtin_amdgcn_mfma_f32_16x16x32_bf16(
                            af[i], bf[j], acc[i][j], 0, 0, 0);
            }
            __syncthreads();
        }
    }

    // ---- epilogue: restage through LDS, coalesced postprocess + store ----
    const int erow = tid >> 5;          // 0..7
    const int ecol = (tid & 31) * 4;    // 0..124, float4 granularity
    const float4 bvec = *(const float4*)&bias[n0 + ecol];

    #pragma unroll
    for (int pass = 0; pass < 2; pass++) {
        if (pass) __syncthreads();      // pass0 Ep reads done before overwrite
        if ((wave >> 1) == pass) {
            #pragma unroll
            for (int i = 0; i < 4; i++)
                #pragma unroll
                for (int j = 0; j < 4; j++)
                    #pragma unroll
                    for (int rg = 0; rg < 4; rg++)
                        Ep[(i * 16 + q * 4 + rg) * 132 + wn + j * 16 + r] =
                            acc[i][j][rg];
        }
        __syncthreads();
        #pragma unroll
        for (int it = 0; it < 8; it++) {
            const int row = it * 8 + erow;   // 0..63 within half-tile
            const long grow = (long)(m0 + pass * 64 + row) * N + n0 + ecol;
            const float4 v = *(const float4*)&Ep[row * 132 + ecol];
            float o0 = v.x + bvec.x, o1 = v.y + bvec.y;
            float o2 = v.z + bvec.z, o3 = v.w + bvec.w;
            if (DO_GELU) {
                o0 = gelu_f(o0); o1 = gelu_f(o1);
                o2 = gelu_f(o2); o3 = gelu_f(o3);
            }
            if (ADD_RES) {
                const float4 rv = *(const float4*)&R[grow];
                o0 += rv.x; o1 += rv.y; o2 += rv.z; o3 += rv.w;
            }
            if (OUT_BF16) {
                ushort4 pk;
                pk.x = f2bf(o0); pk.y = f2bf(o1);
                pk.z = f2bf(o2); pk.w = f2bf(o3);
                *(ushort4*)((unsigned short*)C + grow) = pk;
            } else {
                *(float4*)((float*)C + grow) = make_float4(o0, o1, o2, o3);
            }
        }
    }
}

// ---------------------------------------------------------------------------
// WT[l][n][k] = (bf16) W[l][k][n]
// ---------------------------------------------------------------------------
__global__ __launch_bounds__(256)
void transpose_cast_k(const float* __restrict__ W, __hip_bfloat16* __restrict__ WT,
                      int K, int N) {
    __shared__ float tile[32][33];
    const float* Wl = W + (long)blockIdx.z * K * N;
    __hip_bfloat16* WTl = WT + (long)blockIdx.z * K * N;
    const int n0 = blockIdx.x * 32, k0 = blockIdx.y * 32;
    const int tx = threadIdx.x & 31, ty = threadIdx.x >> 5;
    for (int rr = ty; rr < 32; rr += 8)
        tile[rr][tx] = Wl[(long)(k0 + rr) * N + n0 + tx];
    __syncthreads();
    for (int rr = ty; rr < 32; rr += 8)
        WTl[(long)(n0 + rr) * K + k0 + tx] = __float2bfloat16(tile[tx][rr]);
}

// ---------------------------------------------------------------------------
// fp32 tiled GEMM (in-proj only: M=16384, N=512, K=32)
// ---------------------------------------------------------------------------
template<int DO_GELU>
__global__ __launch_bounds__(256)
void gemm_bias_k(const float* __restrict__ A, long lda,
                 const float* __restrict__ W,
                 const float* __restrict__ bias,
                 float* __restrict__ C,
                 int M, int N, int K) {
    __shared__ float As[16][64];
    __shared__ float Ws[16][64];
    const int tx = threadIdx.x;
    const int ty = threadIdx.y;
    const int tid = ty * 16 + tx;
    const int m0 = blockIdx.y * 64;
    const int n0 = blockIdx.x * 64;
    float acc[4][4] = {};
    for (int k0 = 0; k0 < K; k0 += 16) {
        #pragma unroll
        for (int e = tid; e < 64 * 16; e += 256) {
            int m = e >> 4, k = e & 15;
            float v = 0.f;
            if (m0 + m < M) v = A[(long)(m0 + m) * lda + k0 + k];
            As[k][m] = v;
        }
        #pragma unroll
        for (int e = tid; e < 16 * 64; e += 256) {
            int k = e >> 6, n = e & 63;
            float v = 0.f;
            if (n0 + n < N) v = W[(long)(k0 + k) * N + n0 + n];
            Ws[k][n] = v;
        }
        __syncthreads();
        #pragma unroll
        for (int kk = 0; kk < 16; kk++) {
            float a[4], w[4];
            #pragma unroll
            for (int i = 0; i < 4; i++) a[i] = As[kk][ty * 4 + i];
            #pragma unroll
            for (int j = 0; j < 4; j++) w[j] = Ws[kk][tx * 4 + j];
            #pragma unroll
            for (int i = 0; i < 4; i++)
                #pragma unroll
                for (int j = 0; j < 4; j++)
                    acc[i][j] += a[i] * w[j];
        }
        __syncthreads();
    }
    #pragma unroll
    for (int i = 0; i < 4; i++) {
        int m = m0 + ty * 4 + i;
        if (m >= M) continue;
        #pragma unroll
        for (int j = 0; j < 4; j++) {
            int n = n0 + tx * 4 + j;
            if (n >= N) continue;
            float v = acc[i][j] + bias[n];
            if (DO_GELU) v = gelu_f(v);
            C[(long)m * N + n] = v;
        }
    }
}

// ---------------------------------------------------------------------------
// Wave-per-row LN: H/Hb = layernorm(X)*g+be. 4 rows per 256-thr block.
// ---------------------------------------------------------------------------
__global__ __launch_bounds__(256)
void ln_k(const float* __restrict__ X,
          const float* __restrict__ g,
          const float* __restrict__ be,
          float* __restrict__ H,
          __hip_bfloat16* __restrict__ Hb) {
    const int row = blockIdx.x * 4 + (threadIdx.x >> 6);
    const int lane = threadIdx.x & 63;
    const float* xp = X + (long)row * D_ + lane * 8;
    const float4 a = *(const float4*)xp;
    const float4 c = *(const float4*)(xp + 4);
    float s = a.x + a.y + a.z + a.w + c.x + c.y + c.z + c.w;
    #pragma unroll
    for (int off = 1; off < 64; off <<= 1) s += __shfl_xor(s, off);
    const float mu = s * (1.0f / D_);
    float d[8] = { a.x - mu, a.y - mu, a.z - mu, a.w - mu,
                   c.x - mu, c.y - mu, c.z - mu, c.w - mu };
    float ss = 0.f;
    #pragma unroll
    for (int e = 0; e < 8; e++) ss += d[e] * d[e];
    #pragma unroll
    for (int off = 1; off < 64; off <<= 1) ss += __shfl_xor(ss, off);
    const float inv = 1.0f / sqrtf(ss * (1.0f / D_) + 1e-5f);
    const float4 g0 = *(const float4*)(g + lane * 8);
    const float4 g1 = *(const float4*)(g + lane * 8 + 4);
    const float4 e0 = *(const float4*)(be + lane * 8);
    const float4 e1 = *(const float4*)(be + lane * 8 + 4);
    const float gv[8] = { g0.x, g0.y, g0.z, g0.w, g1.x, g1.y, g1.z, g1.w };
    const float ev[8] = { e0.x, e0.y, e0.z, e0.w, e1.x, e1.y, e1.z, e1.w };
    float o[8];
    short8 pk;
    #pragma unroll
    for (int e = 0; e < 8; e++) {
        o[e] = d[e] * inv * gv[e] + ev[e];
        pk[e] = (short)f2bf(o[e]);
    }
    float* hp = H + (long)row * D_ + lane * 8;
    *(float4*)hp = make_float4(o[0], o[1], o[2], o[3]);
    *(float4*)(hp + 4) = make_float4(o[4], o[5], o[6], o[7]);
    *(short8*)((unsigned short*)Hb + (long)row * D_ + lane * 8) = pk;
}

// ---------------------------------------------------------------------------
// h = gelu(layernorm(X)) + pe ; also bf16 copy hb  (runs once)
// ---------------------------------------------------------------------------
__global__ __launch_bounds__(256)
void ln_gelu_pos_k(const float* __restrict__ X,
                   const float* __restrict__ g,
                   const float* __restrict__ be,
                   float* __restrict__ Hout,
                   __hip_bfloat16* __restrict__ Hb) {
    const int row = blockIdx.x;
    const int s = row & (S_ - 1);
    const int t = threadIdx.x;
    const float* x = X + (long)row * D_;
    float v0 = x[t], v1 = x[t + 256];
    __shared__ float red[256];
    red[t] = v0 + v1;
    __syncthreads();
    for (int off = 128; off; off >>= 1) {
        if (t < off) red[t] += red[t + off];
        __syncthreads();
    }
    float mu = red[0] * (1.0f / D_);
    __syncthreads();
    float d0 = v0 - mu, d1 = v1 - mu;
    red[t] = d0 * d0 + d1 * d1;
    __syncthreads();
    for (int off = 128; off; off >>= 1) {
        if (t < off) red[t] += red[t + off];
        __syncthreads();
    }
    float var = red[0] * (1.0f / D_);
    float inv = 1.0f / sqrtf(var + 1e-5f);
    float o0 = gelu_f(d0 * inv * g[t] + be[t]);
    float o1 = gelu_f(d1 * inv * g[t + 256] + be[t + 256]);
    {
        int d = t, i = d >> 1;
        float dv = expf((float)(2 * i) * (-9.210340371976184f / 512.0f));
        float ang = (float)s * dv;
        o0 += (d & 1) ? cosf(ang) : sinf(ang);
    }
    {
        int d = t + 256, i = d >> 1;
        float dv = expf((float)(2 * i) * (-9.210340371976184f / 512.0f));
        float ang = (float)s * dv;
        o1 += (d & 1) ? cosf(ang) : sinf(ang);
    }
    Hout[(long)row * D_ + t] = o0;
    Hout[(long)row * D_ + t + 256] = o1;
    Hb[(long)row * D_ + t] = __float2bfloat16(o0);
    Hb[(long)row * D_ + t + 256] = __float2bfloat16(o1);
}

// ---------------------------------------------------------------------------
// MFMA flash attention (verified Round-4 structure, unchanged)
// ---------------------------------------------------------------------------
#define LDT 72
__global__ __launch_bounds__(256)
void attn_mfma_k(const __hip_bfloat16* __restrict__ qkv,
                 __hip_bfloat16* __restrict__ O) {
    const int qt = blockIdx.x;
    const int bh = blockIdx.y;
    const int b = bh >> 3, h = bh & (H_ - 1);
    const int tid = threadIdx.x;
    const int wave = tid >> 6, lane = tid & 63;
    const int ln = lane & 15, quad = lane >> 4;
    const int wm = wave * 32;
    const int i0 = qt * 128;

    __shared__ unsigned short Qs[128 * LDT];
    __shared__ unsigned short Ks[64 * LDT];
    __shared__ unsigned short Vt[64 * LDT];
    __shared__ unsigned short Ps[128 * LDT];
    __shared__ float stat[128];

    const unsigned short* base = (const unsigned short*)qkv + (long)b * S_ * (3 * D_);

    {
        const int r0 = tid >> 3, c0 = (tid & 7) * 8;
        #pragma unroll
        for (int i = 0; i < 4; i++) {
            const int rw = i * 32 + r0;
            *(short8*)&Qs[rw * LDT + c0] =
                *(const short8*)(base + (long)(i0 + rw) * (3 * D_) + h * HD_ + c0);
        }
    }

    float m_i[2] = { -INFINITY, -INFINITY };
    float l_i[2] = { 0.f, 0.f };
    floatx4 o_acc[2][4];
    #pragma unroll
    for (int i = 0; i < 2; i++)
        #pragma unroll
        for (int j = 0; j < 4; j++) o_acc[i][j] = (floatx4)0.f;

    const int kr = tid >> 2, kc = (tid & 3) * 16;
    const int vj = tid & 63, vc = (tid >> 6) * 16;

    const int ktmax = 2 * qt + 1;
    for (int kt = 0; kt <= ktmax; kt++) {
        const int j0 = kt * 64;
        {
            const unsigned short* kp = base + (long)(j0 + kr) * (3 * D_) + D_ + h * HD_ + kc;
            *(short8*)&Ks[kr * LDT + kc]     = *(const short8*)(kp);
            *(short8*)&Ks[kr * LDT + kc + 8] = *(const short8*)(kp + 8);
            const unsigned short* vp = base + (long)(j0 + vj) * (3 * D_) + 2 * D_ + h * HD_ + vc;
            short8 v0 = *(const short8*)(vp);
            short8 v1 = *(const short8*)(vp + 8);
            #pragma unroll
            for (int e = 0; e < 8; e++) {
                Vt[(vc + e) * LDT + vj]     = (unsigned short)v0[e];
                Vt[(vc + 8 + e) * LDT + vj] = (unsigned short)v1[e];
            }
        }
        __syncthreads();

        floatx4 sa[4][2];
        #pragma unroll
        for (int mt = 0; mt < 4; mt++)
            #pragma unroll
            for (int nt = 0; nt < 2; nt++) sa[mt][nt] = (floatx4)0.f;
        #pragma unroll
        for (int c = 0; c < 2; c++) {
            short8 kf[4], qf[2];
            #pragma unroll
            for (int mt = 0; mt < 4; mt++)
                kf[mt] = *(const short8*)&Ks[(mt * 16 + ln) * LDT + c * 32 + quad * 8];
            #pragma unroll
            for (int nt = 0; nt < 2; nt++)
                qf[nt] = *(const short8*)&Qs[(wm + nt * 16 + ln) * LDT + c * 32 + quad * 8];
            #pragma unroll
            for (int mt = 0; mt < 4; mt++)
                #pragma unroll
                for (int nt = 0; nt < 2; nt++)
                    sa[mt][nt] = __builtin_amdgcn_mfma_f32_16x16x32_bf16(
                        kf[mt], qf[nt], sa[mt][nt], 0, 0, 0);
        }

        const bool domask = (kt >= 2 * qt);
        #pragma unroll
        for (int nt = 0; nt < 2; nt++) {
            const int qg = i0 + wm + nt * 16 + ln;
            float mx = -INFINITY;
            #pragma unroll
            for (int mt = 0; mt < 4; mt++)
                #pragma unroll
                for (int rg = 0; rg < 4; rg++) {
                    float v = sa[mt][nt][rg] * 0.125f;
                    if (domask && (j0 + mt * 16 + quad * 4 + rg > qg)) v = -INFINITY;
                    sa[mt][nt][rg] = v;
                    mx = fmaxf(mx, v);
                }
            mx = fmaxf(mx, __shfl_xor(mx, 16));
            mx = fmaxf(mx, __shfl_xor(mx, 32));
            const float mn = fmaxf(m_i[nt], mx);
            const float alpha = __expf(m_i[nt] - mn);
            m_i[nt] = mn;
            float ls = 0.f;
            #pragma unroll
            for (int mt = 0; mt < 4; mt++) {
                ushort4 pk;
                float p0 = __expf(sa[mt][nt][0] - mn);
                float p1 = __expf(sa[mt][nt][1] - mn);
                float p2 = __expf(sa[mt][nt][2] - mn);
                float p3 = __expf(sa[mt][nt][3] - mn);
                ls += p0 + p1 + p2 + p3;
                pk.x = f2bf(p0); pk.y = f2bf(p1); pk.z = f2bf(p2); pk.w = f2bf(p3);
                *(ushort4*)&Ps[(wm + nt * 16 + ln) * LDT + mt * 16 + quad * 4] = pk;
            }
            ls += __shfl_xor(ls, 16);
            ls += __shfl_xor(ls, 32);
            l_i[nt] = l_i[nt] * alpha + ls;
            if (quad == 0) stat[wm + nt * 16 + ln] = alpha;
        }

        #pragma unroll
        for (int mt2 = 0; mt2 < 2; mt2++) {
            #pragma unroll
            for (int rg = 0; rg < 4; rg++) {
                const float a = stat[wm + mt2 * 16 + quad * 4 + rg];
                #pragma unroll
                for (int nt = 0; nt < 4; nt++) o_acc[mt2][nt][rg] *= a;
            }
        }

        #pragma unroll
        for (int c = 0; c < 2; c++) {
            short8 pf[2], vf[4];
            #pragma unroll
            for (int mt2 = 0; mt2 < 2; mt2++)
                pf[mt2] = *(const short8*)&Ps[(wm + mt2 * 16 + ln) * LDT + c * 32 + quad * 8];
            #pragma unroll
            for (int nt = 0; nt < 4; nt++)
                vf[nt] = *(const short8*)&Vt[(nt * 16 + ln) * LDT + c * 32 + quad * 8];
            #pragma unroll
            for (int mt2 = 0; mt2 < 2; mt2++)
                #pragma unroll
                for (int nt = 0; nt < 4; nt++)
                    o_acc[mt2][nt] = __builtin_amdgcn_mfma_f32_16x16x32_bf16(
                        pf[mt2], vf[nt], o_acc[mt2][nt], 0, 0, 0);
        }
        __syncthreads();
    }

    if (quad == 0) {
        stat[wm + ln]      = l_i[0];
        stat[wm + 16 + ln] = l_i[1];
    }
    unsigned short* Og = (unsigned short*)O;
    #pragma unroll
    for (int mt2 = 0; mt2 < 2; mt2++) {
        #pragma unroll
        for (int rg = 0; rg < 4; rg++) {
            const float linv = 1.0f / stat[wm + mt2 * 16 + quad * 4 + rg];
            const long row = (long)(b * S_ + i0 + wm + mt2 * 16 + quad * 4 + rg);
            #pragma unroll
            for (int nt = 0; nt < 4; nt++)
                Og[row * D_ + h * HD_ + nt * 16 + ln] =
                    f2bf(o_acc[mt2][nt][rg] * linv);
        }
    }
}

// ---------------------------------------------------------------------------
// Head kernels
// ---------------------------------------------------------------------------
__global__ __launch_bounds__(256)
void head1_k(const float* __restrict__ h, const float* __restrict__ w1,
             const float* __restrict__ b1, float* __restrict__ th) {
    __shared__ float hs[D_];
    const int b = blockIdx.x, n = threadIdx.x;
    const float* hr = h + (long)(b * S_ + S_ - 1) * D_;
    hs[n] = hr[n];
    hs[n + 256] = hr[n + 256];
    __syncthreads();
    float s = 0.f;
    #pragma unroll 8
    for (int k = 0; k < D_; k++) s += hs[k] * w1[(long)k * 256 + n];
    th[b * 256 + n] = gelu_f(s + b1[n]);
}

__global__ __launch_bounds__(64)
void head2_k(const float* __restrict__ th, const float* __restrict__ w2,
             const float* __restrict__ b2, float* __restrict__ out) {
    const int b = blockIdx.x, lane = threadIdx.x;
    const float* t = th + b * 256;
    float s0 = 0.f, s1 = 0.f, s2 = 0.f;
    #pragma unroll
    for (int e = 0; e < 4; e++) {
        const int k = lane * 4 + e;
        const float tv = t[k];
        s0 += tv * w2[k * 3 + 0];
        s1 += tv * w2[k * 3 + 1];
        s2 += tv * w2[k * 3 + 2];
    }
    #pragma unroll
    for (int off = 1; off < 64; off <<= 1) {
        s0 += __shfl_xor(s0, off);
        s1 += __shfl_xor(s1, off);
        s2 += __shfl_xor(s2, off);
    }
    if (lane == 0) {
        out[b * 3 + 0] = s0 + b2[0];
        out[b * 3 + 1] = s1 + b2[1];
        out[b * 3 + 2] = s2 + b2[2];
    }
}

// ---------------------------------------------------------------------------
extern "C" void kernel_launch(void* const* d_in, const int* in_sizes, int n_in,
                              void* d_out, int out_size, void* d_ws, size_t ws_size,
                              hipStream_t stream) {
    const float* x     = (const float*)d_in[0];
    const float* w_in  = (const float*)d_in[1];
    const float* b_in  = (const float*)d_in[2];
    const float* g_in  = (const float*)d_in[3];
    const float* be_in = (const float*)d_in[4];
    const float* w_qkv = (const float*)d_in[5];
    const float* b_qkv = (const float*)d_in[6];
    const float* w_out = (const float*)d_in[7];
    const float* b_out = (const float*)d_in[8];
    const float* g1    = (const float*)d_in[9];
    const float* be1   = (const float*)d_in[10];
    const float* w_ff1 = (const float*)d_in[11];
    const float* b_ff1 = (const float*)d_in[12];
    const float* w_ff2 = (const float*)d_in[13];
    const float* b_ff2 = (const float*)d_in[14];
    const float* g2    = (const float*)d_in[15];
    const float* be2   = (const float*)d_in[16];
    const float* w_h1  = (const float*)d_in[17];
    const float* b_h1  = (const float*)d_in[18];
    const float* w_h2  = (const float*)d_in[19];
    const float* b_h2  = (const float*)d_in[20];
    float* out = (float*)d_out;

    float* h    = (float*)d_ws;
    float* bufB = h + (long)M_ * D_;
    float* th   = bufB + (long)M_ * D_;
    __hip_bfloat16* hb    = (__hip_bfloat16*)(th + 32 * 256);
    __hip_bfloat16* attb  = hb + (long)M_ * D_;
    __hip_bfloat16* bufAb = attb + (long)M_ * D_;
    __hip_bfloat16* qkvT  = bufAb + (long)M_ * FF_;
    __hip_bfloat16* outT  = qkvT + (long)L_ * (3 * D_) * D_;
    __hip_bfloat16* ff1T  = outT + (long)L_ * D_ * D_;
    __hip_bfloat16* ff2T  = ff1T + (long)L_ * FF_ * D_;

    dim3 blk(16, 16);

    transpose_cast_k<<<dim3((3 * D_) / 32, D_ / 32, L_), 256, 0, stream>>>(w_qkv, qkvT, D_, 3 * D_);
    transpose_cast_k<<<dim3(D_ / 32, D_ / 32, L_), 256, 0, stream>>>(w_out, outT, D_, D_);
    transpose_cast_k<<<dim3(FF_ / 32, D_ / 32, L_), 256, 0, stream>>>(w_ff1, ff1T, D_, FF_);
    transpose_cast_k<<<dim3(D_ / 32, FF_ / 32, L_), 256, 0, stream>>>(w_ff2, ff2T, FF_, D_);

    gemm_bias_k<0><<<dim3(D_ / 64, M_ / 64), blk, 0, stream>>>(
        x, IN_, w_in, b_in, bufB, M_, D_, IN_);
    ln_gelu_pos_k<<<M_, 256, 0, stream>>>(bufB, g_in, be_in, h, hb);

    for (int l = 0; l < L_; l++) {
        // qkv -> bf16 bufAb   (PIPE=1: R9 config best for non-GELU GEMMs)
        gemm_mfma_k<0, 1, 0, 1><<<dim3((3 * D_) / 128, M_ / 128), 256, 0, stream>>>(
            hb, qkvT + (long)l * (3 * D_) * D_, b_qkv + l * 3 * D_, nullptr,
            bufAb, 3 * D_, D_);
        attn_mfma_k<<<dim3(S_ / 128, B_ * H_), 256, 0, stream>>>(bufAb, attb);
        // out-proj + residual(h) -> fp32 bufB ; h = LN(bufB)
        gemm_mfma_k<0, 0, 1, 1><<<dim3(D_ / 128, M_ / 128), 256, 0, stream>>>(
            attb, outT + (long)l * D_ * D_, b_out + l * D_, h,
            bufB, D_, D_);
        ln_k<<<M_ / 4, 256, 0, stream>>>(bufB, g1 + l * D_, be1 + l * D_, h, hb);
        // ff1 -> bf16 bufAb (gelu)  (PIPE=0: R8 config, 65us measured best)
        gemm_mfma_k<1, 1, 0, 0><<<dim3(FF_ / 128, M_ / 128), 256, 0, stream>>>(
            hb, ff1T + (long)l * FF_ * D_, b_ff1 + l * FF_, nullptr,
            bufAb, FF_, D_);
        // ff2 + residual(h) -> fp32 bufB ; h = LN(bufB)
        gemm_mfma_k<0, 0, 1, 1><<<dim3(D_ / 128, M_ / 128), 256, 0, stream>>>(
            bufAb, ff2T + (long)l * D_ * FF_, b_ff2 + l * D_, h,
            bufB, D_, FF_);
        ln_k<<<M_ / 4, 256, 0, stream>>>(bufB, g2 + l * D_, be2 + l * D_, h, hb);
    }

    head1_k<<<B_, 256, 0, stream>>>(h, w_h1, b_h1, th);
    head2_k<<<B_, 64, 0, stream>>>(th, w_h2, b_h2, out);
}